// Round 5
// baseline (681.313 us; speedup 1.0000x reference)
//
#include <hip/hip_runtime.h>

#define C_DIM 256
#define K_DIM 1024
#define HW    1024
#define N_TOK 65536
#define OUT_LOSS 16777216
#define OUT_IDXF 16777219

// ---------------------------------------------------------------------------
// Kernel 1: ||z_n||^2 (numpy pairwise_sum replication) and ||e_k||^2
// numpy pairwise for n=256: ps(0:128) + ps(128:256); each 128-block uses 8
// accumulators r[i]=a[i]; r[i]+=a[8j+i] for j=1..15; combine
// ((r0+r1)+(r2+r3))+((r4+r5)+(r6+r7)).  Must NOT contract mul+add to FMA.
// NOTE (r4 analysis): Z-order is argmin-irrelevant (uniform shift across all
// candidates of a token); kept for loss-value fidelity only.
// ---------------------------------------------------------------------------
__global__ void vq_norms(const float* __restrict__ z, const float* __restrict__ e,
                         float* __restrict__ Zarr, float* __restrict__ Bsq) {
#pragma clang fp contract(off)
  const int t = threadIdx.x;
  const int bid = blockIdx.x;
  if (bid < 256) {
    // one thread per token; lanes = consecutive hw -> coalesced strided walk
    const int n = bid * 256 + t;
    const int b = n >> 10, hw = n & 1023;
    const float* p = z + (size_t)b * C_DIM * HW + hw;
    float s[2];
#pragma unroll
    for (int half = 0; half < 2; ++half) {
      float r[8];
#pragma unroll
      for (int i = 0; i < 8; ++i) {
        float v = p[(size_t)(half * 128 + i) * HW];
        r[i] = v * v;
      }
      for (int j = 8; j < 128; j += 8) {
#pragma unroll
        for (int i = 0; i < 8; ++i) {
          float v = p[(size_t)(half * 128 + j + i) * HW];
          float sq = v * v;
          r[i] = r[i] + sq;
        }
      }
      s[half] = ((r[0] + r[1]) + (r[2] + r[3])) + ((r[4] + r[5]) + (r[6] + r[7]));
    }
    Zarr[n] = s[0] + s[1];
  } else {
    const int k = (bid - 256) * 256 + t;  // 0..1023
    const float* p = e + (size_t)k * C_DIM;
    float s[2];
#pragma unroll
    for (int half = 0; half < 2; ++half) {
      float r[8];
#pragma unroll
      for (int i = 0; i < 8; ++i) {
        float v = p[half * 128 + i];
        r[i] = v * v;
      }
      for (int j = 8; j < 128; j += 8) {
#pragma unroll
        for (int i = 0; i < 8; ++i) {
          float v = p[half * 128 + j + i];
          float sq = v * v;
          r[i] = r[i] + sq;
        }
      }
      s[half] = ((r[0] + r[1]) + (r[2] + r[3])) + ((r[4] + r[5]) + (r[6] + r[7]));
    }
    Bsq[k] = s[0] + s[1];
  }
}

// ---------------------------------------------------------------------------
// Kernel 2: fused distance-GEMM + argmin.
// Block: 256 threads, 128 tokens x 128 codes tile; K-tiles of 128 codes,
// c staged in chunks of 32 (LDS c-major, lane-contiguous fragments).
// Per thread: 8 tokens x 8 codes register tile; dot = sequential fp32 FMA
// chain over c ascending (matches Eigen/oneDNN per-output k-order — the only
// accumulation order that matters for argmin agreement, see r4 analysis).
// d = (Z + B) - 2*dot, fp32-rounded exactly like the np broadcast expression.
// ---------------------------------------------------------------------------
#define ES 132  // e_t row stride (floats): 4-way-max staging writes, aligned reads

__global__ __launch_bounds__(256, 2)
void vq_argmin(const float* __restrict__ z, const float* __restrict__ e,
               const float* __restrict__ Zarr, const float* __restrict__ Bsq,
               int* __restrict__ idx_i, float* __restrict__ idx_f) {
  __shared__ __align__(16) float z_t[32 * 128];
  __shared__ __align__(16) float e_t[32 * ES];
  const int t = threadIdx.x;
  const int n0 = blockIdx.x * 128;
  const int b = n0 >> 10;
  const int hw0 = n0 & 1023;
  const float* zb = z + (size_t)b * C_DIM * HW + hw0;  // zb[c*1024 + h]
  const int tn = t & 15, kq = t >> 4;

  float bestd[8];
  int besti[8];
#pragma unroll
  for (int i = 0; i < 8; ++i) { bestd[i] = INFINITY; besti[i] = 0; }

  float Zn[8];
#pragma unroll
  for (int nh = 0; nh < 2; ++nh)
#pragma unroll
    for (int j = 0; j < 4; ++j)
      Zn[nh * 4 + j] = Zarr[n0 + nh * 64 + 4 * tn + j];

  for (int kt = 0; kt < 8; ++kt) {
    float acc[8][8];
#pragma unroll
    for (int i = 0; i < 8; ++i)
#pragma unroll
      for (int j = 0; j < 8; ++j) acc[i][j] = 0.0f;

    for (int ch = 0; ch < 8; ++ch) {
      __syncthreads();  // protect LDS from previous chunk's readers
      // stage z chunk: 32 c-rows x 128 tokens, lane-contiguous b128 writes
      {
        const int c_l = t >> 5;          // 0..7
        const int n_l = (t & 31) * 4;    // 0..124
#pragma unroll
        for (int it = 0; it < 4; ++it) {
          int cc = c_l + 8 * it;
          float4 v = *(const float4*)(zb + (size_t)(ch * 32 + cc) * HW + n_l);
          *(float4*)&z_t[cc * 128 + n_l] = v;
        }
      }
      // stage e chunk transposed: e global [k][c] -> e_t[c][k]
      {
        const int k_l = t >> 3;          // 0..31
        const int c4 = (t & 7) * 4;      // 0..28
#pragma unroll
        for (int it = 0; it < 4; ++it) {
          int kk = k_l + 32 * it;
          float4 v = *(const float4*)(e + (size_t)(kt * 128 + kk) * C_DIM + ch * 32 + c4);
          e_t[(c4 + 0) * ES + kk] = v.x;
          e_t[(c4 + 1) * ES + kk] = v.y;
          e_t[(c4 + 2) * ES + kk] = v.z;
          e_t[(c4 + 3) * ES + kk] = v.w;
        }
      }
      __syncthreads();
#pragma unroll 8
      for (int c = 0; c < 32; ++c) {
        float4 za = *(const float4*)&z_t[c * 128 + 4 * tn];
        float4 zc = *(const float4*)&z_t[c * 128 + 64 + 4 * tn];
        float4 ea = *(const float4*)&e_t[c * ES + 4 * kq];
        float4 eb = *(const float4*)&e_t[c * ES + 64 + 4 * kq];
        float zf[8] = {za.x, za.y, za.z, za.w, zc.x, zc.y, zc.z, zc.w};
        float ef[8] = {ea.x, ea.y, ea.z, ea.w, eb.x, eb.y, eb.z, eb.w};
#pragma unroll
        for (int ni = 0; ni < 8; ++ni)
#pragma unroll
          for (int ki = 0; ki < 8; ++ki)
            acc[ni][ki] = fmaf(zf[ni], ef[ki], acc[ni][ki]);
      }
    }
    // epilogue for this k-tile: d = (Z+B) - 2*dot, running argmin (k ascending)
#pragma unroll
    for (int kh = 0; kh < 2; ++kh)
#pragma unroll
      for (int kj = 0; kj < 4; ++kj) {
        const int kg = kt * 128 + kh * 64 + 4 * kq + kj;
        const float Bv = Bsq[kg];
#pragma unroll
        for (int ni = 0; ni < 8; ++ni) {
          float t1 = Zn[ni] + Bv;
          float d = t1 - 2.0f * acc[ni][kh * 4 + kj];
          if (d < bestd[ni]) { bestd[ni] = d; besti[ni] = kg; }
        }
      }
  }

  // cross-thread (over kq) argmin reduction; tie -> smallest k (np first-min)
  __syncthreads();
  float* red_d = z_t;           // 128*16 floats
  int* red_i = (int*)e_t;       // 128*16 ints
#pragma unroll
  for (int nh = 0; nh < 2; ++nh)
#pragma unroll
    for (int j = 0; j < 4; ++j) {
      int nl = nh * 64 + 4 * tn + j;
      red_d[nl * 16 + kq] = bestd[nh * 4 + j];
      red_i[nl * 16 + kq] = besti[nh * 4 + j];
    }
  __syncthreads();
  if (t < 128) {
    float bd = red_d[t * 16];
    int bi = red_i[t * 16];
#pragma unroll
    for (int q = 1; q < 16; ++q) {
      float d = red_d[t * 16 + q];
      int i2 = red_i[t * 16 + q];
      if (d < bd || (d == bd && i2 < bi)) { bd = d; bi = i2; }
    }
    idx_i[n0 + t] = bi;
    idx_f[n0 + t] = (float)bi;
  }
}

// ---------------------------------------------------------------------------
// Kernel 3: gather zq = e[idx], write zq_st = z + (zq - z) back in (b,c,h,w)
// layout, accumulate sum((zq-z)^2) into a double via atomics.
// 32 tokens per block; e rows staged in LDS (stride 257 -> conflict-free).
// ---------------------------------------------------------------------------
__global__ __launch_bounds__(256, 2)
void vq_out(const float* __restrict__ z, const float* __restrict__ e,
            const int* __restrict__ idx, float* __restrict__ out,
            double* __restrict__ sum) {
  __shared__ float e_ld[32 * 257];
  __shared__ int idx_l[32];
  const int t = threadIdx.x;
  const int n0 = blockIdx.x * 32;
  const int b = n0 >> 10;
  const int hw0 = n0 & 1023;
  if (t < 32) idx_l[t] = idx[n0 + t];
  __syncthreads();
  {
    const int tokb = t & 3;
    const int c4 = (t >> 2) * 4;  // 0..252
#pragma unroll
    for (int it = 0; it < 8; ++it) {
      int tk = 4 * it + tokb;
      float4 v = *(const float4*)(e + (size_t)idx_l[tk] * C_DIM + c4);
      e_ld[tk * 257 + c4 + 0] = v.x;
      e_ld[tk * 257 + c4 + 1] = v.y;
      e_ld[tk * 257 + c4 + 2] = v.z;
      e_ld[tk * 257 + c4 + 3] = v.w;
    }
  }
  __syncthreads();
  const size_t zbase = (size_t)b * C_DIM * HW + hw0;
  const int h = t & 31;
  const int cq = t >> 5;  // 0..7
  float lsum = 0.0f;
  for (int cc = 0; cc < 32; ++cc) {
    int c = cc * 8 + cq;
    float zv = z[zbase + (size_t)c * HW + h];
    float ev = e_ld[h * 257 + c];
    float diff = ev - zv;
    lsum = fmaf(diff, diff, lsum);
    out[zbase + (size_t)c * HW + h] = zv + diff;  // z + (zq - z), like the ref
  }
#pragma unroll
  for (int off = 32; off > 0; off >>= 1) lsum += __shfl_down(lsum, off);
  if ((t & 63) == 0) atomicAdd(sum, (double)lsum);
}

// ---------------------------------------------------------------------------
// Kernel 4: finalize the three scalars.
// ---------------------------------------------------------------------------
__global__ void vq_fin(const double* __restrict__ sum, float* __restrict__ out) {
  double m = *sum / 16777216.0;
  float mf = (float)m;
  float commit = 0.25f * mf;
  out[OUT_LOSS] = commit + mf;      // loss = commitment + codebook
  out[OUT_LOSS + 1] = commit;       // commitment
  out[OUT_LOSS + 2] = mf;           // codebook
}

extern "C" void kernel_launch(void* const* d_in, const int* in_sizes, int n_in,
                              void* d_out, int out_size, void* d_ws, size_t ws_size,
                              hipStream_t stream) {
  (void)in_sizes; (void)n_in; (void)out_size; (void)ws_size;
  const float* z = (const float*)d_in[0];
  const float* e = (const float*)d_in[1];
  float* out = (float*)d_out;
  // ws layout: [0,16) double loss-sum | Zarr 65536 f | Bsq 1024 f | idx 65536 i
  double* sum = (double*)d_ws;
  float* Zarr = (float*)((char*)d_ws + 16);
  float* Bsq = Zarr + N_TOK;
  int* idxw = (int*)(Bsq + K_DIM);

  hipMemsetAsync(d_ws, 0, 16, stream);
  vq_norms<<<260, 256, 0, stream>>>(z, e, Zarr, Bsq);
  vq_argmin<<<512, 256, 0, stream>>>(z, e, Zarr, Bsq, idxw, out + OUT_IDXF);
  vq_out<<<2048, 256, 0, stream>>>(z, e, idxw, out, sum);
  vq_fin<<<1, 1, 0, stream>>>(sum, out);
}

// Round 10
// 489.317 us; speedup vs baseline: 1.3924x; 1.3924x over previous
//
#include <hip/hip_runtime.h>

#define C_DIM 256
#define K_DIM 1024
#define HW    1024
#define N_TOK 65536
#define OUT_LOSS 16777216
#define OUT_IDXF 16777219
#define MARGIN 4e-3f

typedef __attribute__((ext_vector_type(4))) float f4;
typedef __attribute__((ext_vector_type(4))) int   i4;
typedef __attribute__((ext_vector_type(8))) short short8;
typedef __attribute__((ext_vector_type(4))) float f32x4;

// ws layout (new path)
#define OFF_SUM     0
#define OFF_ZARR    16
#define OFF_BSQ     262160
#define OFF_RES     266256
#define OFF_BITMAP  790544
#define OFF_IDX     9179152
#define OFF_ZT      9441296
#define OFF_EBF     42995728
#define WS_NEED     43520016ULL
#define OFF_ZTF     43520016
#define WS_NEED2    110628880ULL   // + 64MB fp32 token-major z copy

__device__ inline unsigned short f2bf(float f) {  // RNE f32->bf16 (finite inputs)
  unsigned x = __float_as_uint(f);
  x += 0x7fffu + ((x >> 16) & 1u);
  return (unsigned short)(x >> 16);
}

// ===========================================================================
// NEW PATH
// ===========================================================================

// K1: fused z-transpose->bf16 (+optional exact fp32 token-major copy) +
// exact pairwise norms; e bf16-convert + ||e||^2.
__global__ __launch_bounds__(256)
void vq_prep(const float* __restrict__ z, const float* __restrict__ e,
             float* __restrict__ Zarr, float* __restrict__ Bsq,
             unsigned short* __restrict__ zT, unsigned short* __restrict__ ebf,
             float* __restrict__ zTf) {
  const int t = threadIdx.x;
  const int bid = blockIdx.x;
  if (bid < 2048) {
    __shared__ float lds[32][257];
    __shared__ float sh[32][2];
    const int n0 = bid * 32;
    const int b = n0 >> 10, h0 = n0 & 1023;
    const float* zb = z + (size_t)b * (C_DIM * HW) + h0;
#pragma unroll
    for (int it = 0; it < 8; ++it) {
      int m = t + 256 * it;      // 0..2047
      int c = m >> 3;            // 0..255
      int h4 = (m & 7) * 4;      // 0..28
      f4 v = *(const f4*)(zb + (size_t)c * HW + h4);
      lds[h4 + 0][c] = v[0];
      lds[h4 + 1][c] = v[1];
      lds[h4 + 2][c] = v[2];
      lds[h4 + 3][c] = v[3];
    }
    __syncthreads();
    if (t < 64) {  // exact numpy-pairwise halves (2 threads per token)
      const int r = t & 31, half = t >> 5;
      const float* p = &lds[r][half * 128];
      float s;
      {
#pragma clang fp contract(off)
        float rr[8];
#pragma unroll
        for (int i = 0; i < 8; ++i) rr[i] = p[i] * p[i];
        for (int j = 8; j < 128; j += 8) {
#pragma unroll
          for (int i = 0; i < 8; ++i) {
            float v = p[j + i];
            float sq = v * v;
            rr[i] = rr[i] + sq;
          }
        }
        s = ((rr[0] + rr[1]) + (rr[2] + rr[3])) + ((rr[4] + rr[5]) + (rr[6] + rr[7]));
      }
      sh[r][half] = s;
    }
    __syncthreads();
    if (t < 32) Zarr[n0 + t] = sh[t][0] + sh[t][1];
    // exact fp32 token-major copy (coalesced) for the recheck kernel
    if (zTf) {
#pragma unroll
      for (int it = 0; it < 8; ++it) {
        int m = t + 256 * it;          // 0..2047
        int r = m >> 6;                // 0..31
        int c4 = (m & 63) * 4;         // 0..252
        f4 v = {lds[r][c4 + 0], lds[r][c4 + 1], lds[r][c4 + 2], lds[r][c4 + 3]};
        *(f4*)(zTf + (size_t)(n0 + r) * 256 + c4) = v;
      }
    }
    // convert row-major bf16: zT[token][c]
    const int r = t >> 3, part = t & 7;
#pragma unroll
    for (int it = 0; it < 4; ++it) {
      int c0 = part * 8 + it * 64;
      unsigned w0 = (unsigned)f2bf(lds[r][c0 + 0]) | ((unsigned)f2bf(lds[r][c0 + 1]) << 16);
      unsigned w1 = (unsigned)f2bf(lds[r][c0 + 2]) | ((unsigned)f2bf(lds[r][c0 + 3]) << 16);
      unsigned w2 = (unsigned)f2bf(lds[r][c0 + 4]) | ((unsigned)f2bf(lds[r][c0 + 5]) << 16);
      unsigned w3 = (unsigned)f2bf(lds[r][c0 + 6]) | ((unsigned)f2bf(lds[r][c0 + 7]) << 16);
      i4 pk = {(int)w0, (int)w1, (int)w2, (int)w3};
      *(i4*)(zT + (size_t)(n0 + r) * 256 + c0) = pk;
    }
  } else {
    const int k = (bid - 2048) * 256 + t;  // 0..1023
    const float* p = e + (size_t)k * C_DIM;
    float s[2];
    {
#pragma clang fp contract(off)
#pragma unroll
      for (int half = 0; half < 2; ++half) {
        float r[8];
#pragma unroll
        for (int i = 0; i < 8; ++i) {
          float v = p[half * 128 + i];
          r[i] = v * v;
        }
        for (int j = 8; j < 128; j += 8) {
#pragma unroll
          for (int i = 0; i < 8; ++i) {
            float v = p[half * 128 + j + i];
            float sq = v * v;
            r[i] = r[i] + sq;
          }
        }
        s[half] = ((r[0] + r[1]) + (r[2] + r[3])) + ((r[4] + r[5]) + (r[6] + r[7]));
      }
    }
    Bsq[k] = s[0] + s[1];
    for (int c = 0; c < 256; c += 2) {
      unsigned w = (unsigned)f2bf(p[c]) | ((unsigned)f2bf(p[c + 1]) << 16);
      *(unsigned*)(ebf + (size_t)k * 256 + c) = w;
    }
  }
}

// K2: bf16 MFMA distance pass. Phase1: per-token min(d~). Phase2: capture all
// codes with d~ <= min + MARGIN into bitmap. Block = 128 tokens (4 waves x 32),
// N-loop over 16 e-tiles of 64 codes staged in XOR-swizzled LDS.
__global__ __launch_bounds__(256)
void vq_mfma(const unsigned short* __restrict__ zT, const unsigned short* __restrict__ ebf,
             const float* __restrict__ Zarr, const float* __restrict__ Bsq,
             unsigned* __restrict__ bitmap) {
  __shared__ __align__(16) char els[32768];  // 64 codes x 256 c bf16, swizzled
  const int t = threadIdx.x;
  const int l = t & 63, w = t >> 6;
  const int n0 = blockIdx.x * 128;
  const int wtok = n0 + w * 32;

  // A fragments: 2 M-tiles x 8 k-steps, resident whole kernel
  short8 a0[8], a1[8];
  {
    const char* r0 = (const char*)zT + (size_t)(wtok + (l & 15)) * 512;
    const char* r1 = (const char*)zT + (size_t)(wtok + 16 + (l & 15)) * 512;
#pragma unroll
    for (int kt = 0; kt < 8; ++kt) {
      a0[kt] = *(const short8*)(r0 + kt * 64 + (l >> 4) * 16);
      a1[kt] = *(const short8*)(r1 + kt * 64 + (l >> 4) * 16);
    }
  }
  float Zn[2][4];
#pragma unroll
  for (int mt = 0; mt < 2; ++mt)
#pragma unroll
    for (int j = 0; j < 4; ++j)
      Zn[mt][j] = Zarr[wtok + mt * 16 + (l >> 4) * 4 + j];

  float minv[2][4];
#pragma unroll
  for (int mt = 0; mt < 2; ++mt)
#pragma unroll
    for (int j = 0; j < 4; ++j) minv[mt][j] = INFINITY;

  // ---- phase 1: min ----
  for (int et = 0; et < 16; ++et) {
    __syncthreads();
    {
      const char* src = (const char*)ebf + (size_t)et * 32768;
#pragma unroll
      for (int it = 0; it < 8; ++it) {
        int m = t + 256 * it;
        int row = m >> 5;
        int off = (m * 16) ^ ((row & 7) << 4);
        *(i4*)(els + off) = *(const i4*)(src + m * 16);
      }
    }
    __syncthreads();
#pragma unroll
    for (int nt = 0; nt < 4; ++nt) {
      const int rowl = nt * 16 + (l & 15);
      const int rb = rowl * 512 + (l >> 4) * 16;
      const int swz = (rowl & 7) << 4;
      f32x4 acc0 = {0.f, 0.f, 0.f, 0.f}, acc1 = {0.f, 0.f, 0.f, 0.f};
#pragma unroll
      for (int kt = 0; kt < 8; ++kt) {
        short8 bf = *(const short8*)(els + ((rb + kt * 64) ^ swz));
        acc0 = __builtin_amdgcn_mfma_f32_16x16x32_bf16(a0[kt], bf, acc0, 0, 0, 0);
        acc1 = __builtin_amdgcn_mfma_f32_16x16x32_bf16(a1[kt], bf, acc1, 0, 0, 0);
      }
      const float Bv = Bsq[et * 64 + nt * 16 + (l & 15)];
#pragma unroll
      for (int j = 0; j < 4; ++j) {
        float d0 = (Zn[0][j] + Bv) - 2.0f * acc0[j];
        float d1 = (Zn[1][j] + Bv) - 2.0f * acc1[j];
        minv[0][j] = fminf(minv[0][j], d0);
        minv[1][j] = fminf(minv[1][j], d1);
      }
    }
  }
  // reduce min over the 16 lanes (l&15) sharing the same token rows
#pragma unroll
  for (int off = 1; off < 16; off <<= 1)
#pragma unroll
    for (int mt = 0; mt < 2; ++mt)
#pragma unroll
      for (int j = 0; j < 4; ++j)
        minv[mt][j] = fminf(minv[mt][j], __shfl_xor(minv[mt][j], off));
  float thr[2][4];
#pragma unroll
  for (int mt = 0; mt < 2; ++mt)
#pragma unroll
    for (int j = 0; j < 4; ++j) thr[mt][j] = minv[mt][j] + MARGIN;

  // ---- phase 2: capture ----
  for (int et = 0; et < 16; ++et) {
    __syncthreads();
    {
      const char* src = (const char*)ebf + (size_t)et * 32768;
#pragma unroll
      for (int it = 0; it < 8; ++it) {
        int m = t + 256 * it;
        int row = m >> 5;
        int off = (m * 16) ^ ((row & 7) << 4);
        *(i4*)(els + off) = *(const i4*)(src + m * 16);
      }
    }
    __syncthreads();
#pragma unroll
    for (int nt = 0; nt < 4; ++nt) {
      const int rowl = nt * 16 + (l & 15);
      const int rb = rowl * 512 + (l >> 4) * 16;
      const int swz = (rowl & 7) << 4;
      f32x4 acc0 = {0.f, 0.f, 0.f, 0.f}, acc1 = {0.f, 0.f, 0.f, 0.f};
#pragma unroll
      for (int kt = 0; kt < 8; ++kt) {
        short8 bf = *(const short8*)(els + ((rb + kt * 64) ^ swz));
        acc0 = __builtin_amdgcn_mfma_f32_16x16x32_bf16(a0[kt], bf, acc0, 0, 0, 0);
        acc1 = __builtin_amdgcn_mfma_f32_16x16x32_bf16(a1[kt], bf, acc1, 0, 0, 0);
      }
      const int col = et * 64 + nt * 16 + (l & 15);
      const float Bv = Bsq[col];
#pragma unroll
      for (int j = 0; j < 4; ++j) {
        float d0 = (Zn[0][j] + Bv) - 2.0f * acc0[j];
        float d1 = (Zn[1][j] + Bv) - 2.0f * acc1[j];
        if (d0 <= thr[0][j]) {
          int n = wtok + (l >> 4) * 4 + j;
          atomicOr(&bitmap[n * 32 + (col >> 5)], 1u << (col & 31));
        }
        if (d1 <= thr[1][j]) {
          int n = wtok + 16 + (l >> 4) * 4 + j;
          atomicOr(&bitmap[n * 32 + (col >> 5)], 1u << (col & 31));
        }
      }
    }
  }
}

// K3: exact fp32 recheck of captured candidates. One wave per token; the
// sequential-c FMA chain + (Z+B)-2*acc reproduce the r5-proven-exact pipeline
// bit-for-bit; packed (d_bits<<32|k) atomicMin = first-occurrence argmin.
// z source: zTf (coalesced token-major copy) if available, else strided z.
__global__ __launch_bounds__(256)
void vq_recheck(const float* __restrict__ z, const float* __restrict__ zTf,
                const float* __restrict__ e,
                const float* __restrict__ Zarr, const float* __restrict__ Bsq,
                const unsigned* __restrict__ bitmap,
                unsigned long long* __restrict__ res) {
  __shared__ float zr[4][256];
  const int t = threadIdx.x;
  const int l = t & 63, w = t >> 6;
  const int n = blockIdx.x * 4 + w;
  if (zTf) {
    f4 v = *(const f4*)(zTf + (size_t)n * 256 + l * 4);
    *(f4*)&zr[w][l * 4] = v;
  } else {
    const int b = n >> 10, h = n & 1023;
#pragma unroll
    for (int j = 0; j < 4; ++j)
      zr[w][l + 64 * j] = z[(size_t)b * (C_DIM * HW) + (size_t)(l + 64 * j) * HW + h];
  }
  __syncthreads();
  unsigned wbits = (l < 32) ? bitmap[n * 32 + l] : 0u;
  const float Zf = Zarr[n];
  const float* zz = zr[w];
  while (wbits) {
    int bit = __ffs(wbits) - 1;
    wbits &= wbits - 1;
    int k = l * 32 + bit;
    const float* er = e + (size_t)k * C_DIM;
    float acc = 0.f;
#pragma unroll 8
    for (int c = 0; c < 256; ++c) acc = fmaf(zz[c], er[c], acc);
    float d = (Zf + Bsq[k]) - 2.0f * acc;
    unsigned long long pack =
        ((unsigned long long)__float_as_uint(d) << 32) | (unsigned)k;
    atomicMin(&res[n], pack);
  }
}

// K4: unpack final indices.
__global__ void vq_idx(const unsigned long long* __restrict__ res,
                       int* __restrict__ idx_i, float* __restrict__ idx_f) {
  int n = blockIdx.x * 256 + threadIdx.x;
  int k = (int)(res[n] & 0xffffffffULL);
  idx_i[n] = k;
  idx_f[n] = (float)k;
}

// K5: gather + straight-through write + loss accum, contiguous 512B z/out.
__global__ __launch_bounds__(256)
void vq_out2(const float* __restrict__ z, const float* __restrict__ e,
             const int* __restrict__ idx, float* __restrict__ out,
             double* __restrict__ sum) {
  __shared__ float ech[128][65];
  __shared__ int idxl[128];
  const int t = threadIdx.x;
  const int n0 = blockIdx.x * 128;
  const int b = n0 >> 10, h0 = n0 & 1023;
  if (t < 128) idxl[t] = idx[n0 + t];
  __syncthreads();
  float lsum = 0.f;
  const int cg = t >> 5, h4 = (t & 31) * 4;
  for (int cc = 0; cc < 4; ++cc) {
    const int c0 = cc * 64;
    if (cc) __syncthreads();
#pragma unroll
    for (int it = 0; it < 8; ++it) {
      int m = t + 256 * it;
      int r = m >> 4, c4 = (m & 15) * 4;
      f4 v = *(const f4*)(e + (size_t)idxl[r] * C_DIM + c0 + c4);
      ech[r][c4 + 0] = v[0];
      ech[r][c4 + 1] = v[1];
      ech[r][c4 + 2] = v[2];
      ech[r][c4 + 3] = v[3];
    }
    __syncthreads();
#pragma unroll
    for (int ci = 0; ci < 8; ++ci) {
      int c = c0 + cg * 8 + ci;
      size_t zo = (size_t)b * (C_DIM * HW) + (size_t)c * HW + h0 + h4;
      f4 zv = *(const f4*)(z + zo);
      f4 ov;
#pragma unroll
      for (int i = 0; i < 4; ++i) {
        float diff = ech[h4 + i][c - c0] - zv[i];
        ov[i] = zv[i] + diff;
        lsum = fmaf(diff, diff, lsum);
      }
      *(f4*)(out + zo) = ov;
    }
  }
#pragma unroll
  for (int off = 32; off > 0; off >>= 1) lsum += __shfl_down(lsum, off);
  if ((t & 63) == 0) atomicAdd(sum, (double)lsum);
}

__global__ void vq_fin(const double* __restrict__ sum, float* __restrict__ out) {
  double m = *sum / 16777216.0;
  float mf = (float)m;
  float commit = 0.25f * mf;
  out[OUT_LOSS] = commit + mf;
  out[OUT_LOSS + 1] = commit;
  out[OUT_LOSS + 2] = mf;
}

// ===========================================================================
// OLD PATH (proven round-5 pipeline) — fallback when ws is too small.
// ===========================================================================
__global__ void vq_norms(const float* __restrict__ z, const float* __restrict__ e,
                         float* __restrict__ Zarr, float* __restrict__ Bsq) {
#pragma clang fp contract(off)
  const int t = threadIdx.x;
  const int bid = blockIdx.x;
  if (bid < 256) {
    const int n = bid * 256 + t;
    const int b = n >> 10, hw = n & 1023;
    const float* p = z + (size_t)b * C_DIM * HW + hw;
    float s[2];
#pragma unroll
    for (int half = 0; half < 2; ++half) {
      float r[8];
#pragma unroll
      for (int i = 0; i < 8; ++i) {
        float v = p[(size_t)(half * 128 + i) * HW];
        r[i] = v * v;
      }
      for (int j = 8; j < 128; j += 8) {
#pragma unroll
        for (int i = 0; i < 8; ++i) {
          float v = p[(size_t)(half * 128 + j + i) * HW];
          float sq = v * v;
          r[i] = r[i] + sq;
        }
      }
      s[half] = ((r[0] + r[1]) + (r[2] + r[3])) + ((r[4] + r[5]) + (r[6] + r[7]));
    }
    Zarr[n] = s[0] + s[1];
  } else {
    const int k = (bid - 256) * 256 + t;
    const float* p = e + (size_t)k * C_DIM;
    float s[2];
#pragma unroll
    for (int half = 0; half < 2; ++half) {
      float r[8];
#pragma unroll
      for (int i = 0; i < 8; ++i) {
        float v = p[half * 128 + i];
        r[i] = v * v;
      }
      for (int j = 8; j < 128; j += 8) {
#pragma unroll
        for (int i = 0; i < 8; ++i) {
          float v = p[half * 128 + j + i];
          float sq = v * v;
          r[i] = r[i] + sq;
        }
      }
      s[half] = ((r[0] + r[1]) + (r[2] + r[3])) + ((r[4] + r[5]) + (r[6] + r[7]));
    }
    Bsq[k] = s[0] + s[1];
  }
}

#define ES 132
__global__ __launch_bounds__(256, 2)
void vq_argmin(const float* __restrict__ z, const float* __restrict__ e,
               const float* __restrict__ Zarr, const float* __restrict__ Bsq,
               int* __restrict__ idx_i, float* __restrict__ idx_f) {
  __shared__ __align__(16) float z_t[32 * 128];
  __shared__ __align__(16) float e_t[32 * ES];
  const int t = threadIdx.x;
  const int n0 = blockIdx.x * 128;
  const int b = n0 >> 10;
  const int hw0 = n0 & 1023;
  const float* zb = z + (size_t)b * C_DIM * HW + hw0;
  const int tn = t & 15, kq = t >> 4;
  float bestd[8];
  int besti[8];
#pragma unroll
  for (int i = 0; i < 8; ++i) { bestd[i] = INFINITY; besti[i] = 0; }
  float Zn[8];
#pragma unroll
  for (int nh = 0; nh < 2; ++nh)
#pragma unroll
    for (int j = 0; j < 4; ++j)
      Zn[nh * 4 + j] = Zarr[n0 + nh * 64 + 4 * tn + j];
  for (int kt = 0; kt < 8; ++kt) {
    float acc[8][8];
#pragma unroll
    for (int i = 0; i < 8; ++i)
#pragma unroll
      for (int j = 0; j < 8; ++j) acc[i][j] = 0.0f;
    for (int ch = 0; ch < 8; ++ch) {
      __syncthreads();
      {
        const int c_l = t >> 5;
        const int n_l = (t & 31) * 4;
#pragma unroll
        for (int it = 0; it < 4; ++it) {
          int cc = c_l + 8 * it;
          f4 v = *(const f4*)(zb + (size_t)(ch * 32 + cc) * HW + n_l);
          *(f4*)&z_t[cc * 128 + n_l] = v;
        }
      }
      {
        const int k_l = t >> 3;
        const int c4 = (t & 7) * 4;
#pragma unroll
        for (int it = 0; it < 4; ++it) {
          int kk = k_l + 32 * it;
          f4 v = *(const f4*)(e + (size_t)(kt * 128 + kk) * C_DIM + ch * 32 + c4);
          e_t[(c4 + 0) * ES + kk] = v[0];
          e_t[(c4 + 1) * ES + kk] = v[1];
          e_t[(c4 + 2) * ES + kk] = v[2];
          e_t[(c4 + 3) * ES + kk] = v[3];
        }
      }
      __syncthreads();
#pragma unroll 8
      for (int c = 0; c < 32; ++c) {
        f4 za = *(const f4*)&z_t[c * 128 + 4 * tn];
        f4 zc = *(const f4*)&z_t[c * 128 + 64 + 4 * tn];
        f4 ea = *(const f4*)&e_t[c * ES + 4 * kq];
        f4 eb = *(const f4*)&e_t[c * ES + 64 + 4 * kq];
        float zf[8] = {za[0], za[1], za[2], za[3], zc[0], zc[1], zc[2], zc[3]};
        float ef[8] = {ea[0], ea[1], ea[2], ea[3], eb[0], eb[1], eb[2], eb[3]};
#pragma unroll
        for (int ni = 0; ni < 8; ++ni)
#pragma unroll
          for (int ki = 0; ki < 8; ++ki)
            acc[ni][ki] = fmaf(zf[ni], ef[ki], acc[ni][ki]);
      }
    }
#pragma unroll
    for (int kh = 0; kh < 2; ++kh)
#pragma unroll
      for (int kj = 0; kj < 4; ++kj) {
        const int kg = kt * 128 + kh * 64 + 4 * kq + kj;
        const float Bv = Bsq[kg];
#pragma unroll
        for (int ni = 0; ni < 8; ++ni) {
          float t1 = Zn[ni] + Bv;
          float d = t1 - 2.0f * acc[ni][kh * 4 + kj];
          if (d < bestd[ni]) { bestd[ni] = d; besti[ni] = kg; }
        }
      }
  }
  __syncthreads();
  float* red_d = z_t;
  int* red_i = (int*)e_t;
#pragma unroll
  for (int nh = 0; nh < 2; ++nh)
#pragma unroll
    for (int j = 0; j < 4; ++j) {
      int nl = nh * 64 + 4 * tn + j;
      red_d[nl * 16 + kq] = bestd[nh * 4 + j];
      red_i[nl * 16 + kq] = besti[nh * 4 + j];
    }
  __syncthreads();
  if (t < 128) {
    float bd = red_d[t * 16];
    int bi = red_i[t * 16];
#pragma unroll
    for (int q = 1; q < 16; ++q) {
      float d = red_d[t * 16 + q];
      int i2 = red_i[t * 16 + q];
      if (d < bd || (d == bd && i2 < bi)) { bd = d; bi = i2; }
    }
    idx_i[n0 + t] = bi;
    idx_f[n0 + t] = (float)bi;
  }
}

__global__ __launch_bounds__(256, 2)
void vq_out(const float* __restrict__ z, const float* __restrict__ e,
            const int* __restrict__ idx, float* __restrict__ out,
            double* __restrict__ sum) {
  __shared__ float e_ld[32 * 257];
  __shared__ int idx_l[32];
  const int t = threadIdx.x;
  const int n0 = blockIdx.x * 32;
  const int b = n0 >> 10;
  const int hw0 = n0 & 1023;
  if (t < 32) idx_l[t] = idx[n0 + t];
  __syncthreads();
  {
    const int tokb = t & 3;
    const int c4 = (t >> 2) * 4;
#pragma unroll
    for (int it = 0; it < 8; ++it) {
      int tk = 4 * it + tokb;
      f4 v = *(const f4*)(e + (size_t)idx_l[tk] * C_DIM + c4);
      e_ld[tk * 257 + c4 + 0] = v[0];
      e_ld[tk * 257 + c4 + 1] = v[1];
      e_ld[tk * 257 + c4 + 2] = v[2];
      e_ld[tk * 257 + c4 + 3] = v[3];
    }
  }
  __syncthreads();
  const size_t zbase = (size_t)b * C_DIM * HW + hw0;
  const int h = t & 31;
  const int cq = t >> 5;
  float lsum = 0.0f;
  for (int cc = 0; cc < 32; ++cc) {
    int c = cc * 8 + cq;
    float zv = z[zbase + (size_t)c * HW + h];
    float ev = e_ld[h * 257 + c];
    float diff = ev - zv;
    lsum = fmaf(diff, diff, lsum);
    out[zbase + (size_t)c * HW + h] = zv + diff;
  }
#pragma unroll
  for (int off = 32; off > 0; off >>= 1) lsum += __shfl_down(lsum, off);
  if ((t & 63) == 0) atomicAdd(sum, (double)lsum);
}

// ===========================================================================
extern "C" void kernel_launch(void* const* d_in, const int* in_sizes, int n_in,
                              void* d_out, int out_size, void* d_ws, size_t ws_size,
                              hipStream_t stream) {
  (void)in_sizes; (void)n_in; (void)out_size;
  const float* z = (const float*)d_in[0];
  const float* e = (const float*)d_in[1];
  float* out = (float*)d_out;
  char* ws = (char*)d_ws;

  if (ws_size >= WS_NEED) {
    double* sum = (double*)(ws + OFF_SUM);
    float* Zarr = (float*)(ws + OFF_ZARR);
    float* Bsq = (float*)(ws + OFF_BSQ);
    unsigned long long* res = (unsigned long long*)(ws + OFF_RES);
    unsigned* bitmap = (unsigned*)(ws + OFF_BITMAP);
    int* idxw = (int*)(ws + OFF_IDX);
    unsigned short* zT = (unsigned short*)(ws + OFF_ZT);
    unsigned short* ebf = (unsigned short*)(ws + OFF_EBF);
    float* zTf = (ws_size >= WS_NEED2) ? (float*)(ws + OFF_ZTF) : nullptr;

    hipMemsetAsync(sum, 0, 16, stream);
    hipMemsetAsync(res, 0xFF, 524288, stream);
    hipMemsetAsync(bitmap, 0, 8388608, stream);
    vq_prep<<<2052, 256, 0, stream>>>(z, e, Zarr, Bsq, zT, ebf, zTf);
    vq_mfma<<<512, 256, 0, stream>>>(zT, ebf, Zarr, Bsq, bitmap);
    vq_recheck<<<16384, 256, 0, stream>>>(z, zTf, e, Zarr, Bsq, bitmap, res);
    vq_idx<<<256, 256, 0, stream>>>(res, idxw, out + OUT_IDXF);
    vq_out2<<<512, 256, 0, stream>>>(z, e, idxw, out, sum);
    vq_fin<<<1, 1, 0, stream>>>(sum, out);
  } else {
    double* sum = (double*)d_ws;
    float* Zarr = (float*)(ws + 16);
    float* Bsq = Zarr + N_TOK;
    int* idxw = (int*)(Bsq + K_DIM);
    hipMemsetAsync(d_ws, 0, 16, stream);
    vq_norms<<<260, 256, 0, stream>>>(z, e, Zarr, Bsq);
    vq_argmin<<<512, 256, 0, stream>>>(z, e, Zarr, Bsq, idxw, out + OUT_IDXF);
    vq_out<<<2048, 256, 0, stream>>>(z, e, idxw, out, sum);
    vq_fin<<<1, 1, 0, stream>>>(sum, out);
  }
}